// Round 5
// baseline (58.047 us; speedup 1.0000x reference)
//
#include <hip/hip_runtime.h>
#include <hip/hip_bf16.h>

#define NC 4096
#define NK 1024
#define NT (NC / 128)              // 32 row/col tiles
#define NBLK (NT * (NT + 1) / 2)   // 528 upper-triangular blocks (= 8 XCDs * 66)
#define NSTEP 8                    // 1024 K / BK=128

static constexpr float MARGIN = 0.0001f;

typedef __attribute__((ext_vector_type(4))) int i32x4;
typedef __attribute__((ext_vector_type(8))) int i32x8;
typedef __attribute__((ext_vector_type(16))) float f32x16;

// Async 16B global -> LDS. LDS dest is wave-uniform; HW writes dst + lane*16.
__device__ inline void gload16(const void* g, void* l) {
    __builtin_amdgcn_global_load_lds(
        (const __attribute__((address_space(1))) void*)g,
        (__attribute__((address_space(3))) void*)l,
        16, 0, 0);
}

// fp4 e2m1 quantize (round via thresholds): values {0,.5,1,1.5,2,3,4,6}, sign bit 3.
__device__ inline uint q4(float x) {
    const float a = fabsf(x);
    uint c = (a >= 0.25f) + (a >= 0.75f) + (a >= 1.25f) + (a >= 1.75f) +
             (a >= 2.5f) + (a >= 3.5f) + (a >= 5.0f);
    return c | (x < 0.f ? 8u : 0u);
}

// One block per row: quantize f32 row -> fp4 (packed nibbles, elem k at byte k/2,
// even k in low nibble), and compute exact f32 sum of squares.
__global__ __launch_bounds__(256) void cast_sq_kernel(const float* __restrict__ x,
                                                      uchar* __restrict__ xq,
                                                      float* __restrict__ sq) {
    const int row = blockIdx.x;
    const int t = threadIdx.x;
    const float4 v = reinterpret_cast<const float4*>(x + (size_t)row * NK)[t];
    float s = v.x * v.x + v.y * v.y + v.z * v.z + v.w * v.w;
    const uint u = q4(v.x) | (q4(v.y) << 4) | (q4(v.z) << 8) | (q4(v.w) << 12);
    reinterpret_cast<ushort*>(xq + (size_t)row * 512)[t] = (ushort)u;

    #pragma unroll
    for (int off = 32; off > 0; off >>= 1) s += __shfl_down(s, off);
    __shared__ float red[4];
    const int lane = t & 63, wid = t >> 6;
    if (lane == 0) red[wid] = s;
    __syncthreads();
    if (t == 0) sq[row] = red[0] + red[1] + red[2] + red[3];
}

__global__ void zero_kernel(float* out) { out[0] = 0.f; }

// Upper-triangular tiled syrk in MX-fp4 (constant scale 1.0) with fused hinge
// reduction. 128x128 tile, BK=128, 8 K-steps, triple-buffered LDS with 2-deep
// prefetch + counted vmcnt. 4 waves (2x2), each 64x64 via 2x2 frags of
// mfma_scale_f32_32x32x64_f8f6f4. 16B-granule swizzle g^=(row>>1)&3 on both the
// global source and the ds_read side (rule #21) -> conflict-free b128 reads.
__global__ __launch_bounds__(256) void gram_hinge_kernel(const uchar* __restrict__ xq,
                                                         const float* __restrict__ sq,
                                                         float* __restrict__ out) {
    // XCD-aware chunking: 528 = 8 * 66 exactly -> bijective.
    const int wgid = (blockIdx.x & 7) * (NBLK / 8) + (blockIdx.x >> 3);
    int rem = wgid;
    int bi = 0;
    while (rem >= NT - bi) { rem -= NT - bi; ++bi; }
    const int bj = bi + rem;

    __shared__ uchar As[3][128 * 64];  // 3 x 8 KB (128 rows x 64 B = 128 fp4 K)
    __shared__ uchar Bs[3][128 * 64];
    __shared__ float red[4];

    const int tid = threadIdx.x;
    const int lane = tid & 63, wid = tid >> 6;
    const int wr = wid >> 1, wc = wid & 1;
    const int hi = lane >> 5;

    const int rowA0 = bi * 128;
    const int rowB0 = bj * 128;

    f32x16 acc[2][2];
    #pragma unroll
    for (int m = 0; m < 2; ++m)
        #pragma unroll
        for (int n = 0; n < 2; ++n)
            #pragma unroll
            for (int e = 0; e < 16; ++e)
                acc[m][n][e] = 0.f;

    // Stage one K-tile (A,B each 128 rows x 64 B = 512 granules of 16B).
    // LDS granule G=(row=G>>2, cl=G&3) holds global granule cg = cl ^ ((row>>1)&3).
    // 2 A + 2 B instrs per wave per step.
    auto STAGE = [&](int buf, int kt) {
        #pragma unroll
        for (int u = 0; u < 2; ++u) {
            const int G = wid * 128 + u * 64 + lane;
            const int row = G >> 2;
            const int cg = (G & 3) ^ ((row >> 1) & 3);
            gload16(xq + (size_t)(rowA0 + row) * 512 + kt * 64 + cg * 16,
                    &As[buf][(wid * 128 + u * 64) * 16]);
            gload16(xq + (size_t)(rowB0 + row) * 512 + kt * 64 + cg * 16,
                    &Bs[buf][(wid * 128 + u * 64) * 16]);
        }
    };

    auto COMPUTE = [&](int buf) {
        #pragma unroll
        for (int kk = 0; kk < 2; ++kk) {
            i32x8 a[2], b[2];
            #pragma unroll
            for (int m = 0; m < 2; ++m) {
                const int row = wr * 64 + m * 32 + (lane & 31);
                const int gp = (kk * 2 + hi) ^ ((row >> 1) & 3);
                const i32x4 t4 = *reinterpret_cast<const i32x4*>(&As[buf][row * 64 + gp * 16]);
                i32x8 av;
                av[0] = t4[0]; av[1] = t4[1]; av[2] = t4[2]; av[3] = t4[3];
                av[4] = 0; av[5] = 0; av[6] = 0; av[7] = 0;
                a[m] = av;
            }
            #pragma unroll
            for (int n = 0; n < 2; ++n) {
                const int row = wc * 64 + n * 32 + (lane & 31);
                const int gp = (kk * 2 + hi) ^ ((row >> 1) & 3);
                const i32x4 t4 = *reinterpret_cast<const i32x4*>(&Bs[buf][row * 64 + gp * 16]);
                i32x8 bv;
                bv[0] = t4[0]; bv[1] = t4[1]; bv[2] = t4[2]; bv[3] = t4[3];
                bv[4] = 0; bv[5] = 0; bv[6] = 0; bv[7] = 0;
                b[n] = bv;
            }
            #pragma unroll
            for (int m = 0; m < 2; ++m)
                #pragma unroll
                for (int n = 0; n < 2; ++n)
                    acc[m][n] = __builtin_amdgcn_mfma_scale_f32_32x32x64_f8f6f4(
                        a[m], b[n], acc[m][n], 4, 4,            // cbsz=fp4, blgp=fp4
                        0, 0x7f7f7f7f, 0, 0x7f7f7f7f);          // scale = 1.0 (all bytes)
        }
    };

    // 2-deep prefetch pipeline over 8 K-steps, triple-buffered.
    STAGE(0, 0);
    STAGE(1, 1);
    #pragma unroll
    for (int kt = 0; kt < NSTEP; ++kt) {
        if (kt < NSTEP - 2) {
            STAGE((kt + 2) % 3, kt + 2);                      // 4 new vmem ops
            asm volatile("s_waitcnt vmcnt(8)" ::: "memory");  // tile kt's 4 oldest done
        } else if (kt == NSTEP - 2) {
            asm volatile("s_waitcnt vmcnt(4)" ::: "memory");
        } else {
            asm volatile("s_waitcnt vmcnt(0)" ::: "memory");
        }
        __builtin_amdgcn_s_barrier();
        __builtin_amdgcn_sched_barrier(0);
        COMPUTE(kt % 3);
        __builtin_amdgcn_sched_barrier(0);
        __builtin_amdgcn_s_barrier();   // all reads of this buf done -> overwrite ok
    }

    // Fused epilogue: d2 = sq[i] + sq[j] - 2*g ; hinge; mask i<j ; reduce.
    // C/D layout (32x32): col = lane&31, row = (r&3) + 8*(r>>2) + 4*(lane>>5)  [m74/m101]
    float local = 0.f;
    #pragma unroll
    for (int n = 0; n < 2; ++n) {
        const int j = rowB0 + wc * 64 + n * 32 + (lane & 31);
        const float sqj = sq[j];
        #pragma unroll
        for (int m = 0; m < 2; ++m) {
            const int ibase = rowA0 + wr * 64 + m * 32 + 4 * hi;
            #pragma unroll
            for (int r = 0; r < 16; ++r) {
                const int i = ibase + (r & 3) + 8 * (r >> 2);
                if (i < j) {
                    const float d2 = sq[i] + sqj - 2.f * acc[m][n][r];
                    const float d = sqrtf(fmaxf(d2, 0.f));
                    local += fmaxf(MARGIN - d, 0.f);
                }
            }
        }
    }
    #pragma unroll
    for (int off = 32; off > 0; off >>= 1) local += __shfl_down(local, off);
    if (lane == 0) red[wid] = local;
    __syncthreads();
    if (tid == 0) atomicAdd(out, red[0] + red[1] + red[2] + red[3]);
}

extern "C" void kernel_launch(void* const* d_in, const int* in_sizes, int n_in,
                              void* d_out, int out_size, void* d_ws, size_t ws_size,
                              hipStream_t stream) {
    const float* x = (const float*)d_in[0];
    float* out = (float*)d_out;
    uchar* xq = (uchar*)d_ws;                                   // 2 MB fp4 matrix
    float* sq = (float*)((char*)d_ws + (size_t)NC * 512);       // 16 KB row norms

    cast_sq_kernel<<<NC, 256, 0, stream>>>(x, xq, sq);
    zero_kernel<<<1, 1, 0, stream>>>(out);
    gram_hinge_kernel<<<NBLK, 256, 0, stream>>>(xq, sq, out);
}

// Round 6
// 27.610 us; speedup vs baseline: 2.1023x; 2.1023x over previous
//
#include <hip/hip_runtime.h>
#include <hip/hip_bf16.h>

#define NC 4096
#define NK 1024
#define TS 64                      // tile size (rows and cols)
#define NT (NC / TS)               // 64 tiles per dim
#define NBLK (NT * (NT + 1) / 2)   // 2080 upper-triangular blocks = 8 XCDs * 260
#define NSTEP 8                    // 1024 K / BK=128 (64 B fp4 per row-step)
#define NPART 128                  // scattered partial-sum slots (cacheline-spaced)

static constexpr float MARGIN = 0.0001f;

typedef __attribute__((ext_vector_type(4))) int i32x4;
typedef __attribute__((ext_vector_type(8))) int i32x8;
typedef __attribute__((ext_vector_type(16))) float f32x16;

// Async 16B global -> LDS. LDS dest is wave-uniform; HW writes dst + lane*16.
__device__ inline void gload16(const void* g, void* l) {
    __builtin_amdgcn_global_load_lds(
        (const __attribute__((address_space(1))) void*)g,
        (__attribute__((address_space(3))) void*)l,
        16, 0, 0);
}

// fp4 e2m1 quantize (round to nearest via thresholds): {0,.5,1,1.5,2,3,4,6}, sign bit 3.
__device__ inline uint q4(float x) {
    const float a = fabsf(x);
    uint c = (a >= 0.25f) + (a >= 0.75f) + (a >= 1.25f) + (a >= 1.75f) +
             (a >= 2.5f) + (a >= 3.5f) + (a >= 5.0f);
    return c | (x < 0.f ? 8u : 0u);
}

// 512 blocks x 4 waves; each wave quantizes 2 full rows (f32 -> packed fp4)
// and writes the exact f32 row norm. Block 0 also zeroes the partial slots.
__global__ __launch_bounds__(256) void cast_sq_kernel(const float* __restrict__ x,
                                                      uchar* __restrict__ xq,
                                                      float* __restrict__ sq,
                                                      float* __restrict__ part) {
    const int tid = threadIdx.x, lane = tid & 63, wid = tid >> 6;
    if (blockIdx.x == 0 && tid < NPART) part[tid * 16] = 0.f;
    const int wg = blockIdx.x * 4 + wid;   // 2048 waves
    #pragma unroll
    for (int it = 0; it < 2; ++it) {
        const int row = wg + it * 2048;
        float s = 0.f;
        #pragma unroll
        for (int c = 0; c < 4; ++c) {
            const float4 v = reinterpret_cast<const float4*>(x + (size_t)row * NK)[lane + c * 64];
            s += v.x * v.x + v.y * v.y + v.z * v.z + v.w * v.w;
            const ushort u = (ushort)(q4(v.x) | (q4(v.y) << 4) | (q4(v.z) << 8) | (q4(v.w) << 12));
            reinterpret_cast<ushort*>(xq + (size_t)row * 512)[lane + c * 64] = u;
        }
        #pragma unroll
        for (int off = 32; off > 0; off >>= 1) s += __shfl_down(s, off);
        if (lane == 0) sq[row] = s;
    }
}

__global__ void final_kernel(const float* __restrict__ part, float* __restrict__ out) {
    float v = part[threadIdx.x * 16];
    #pragma unroll
    for (int off = 32; off > 0; off >>= 1) v += __shfl_down(v, off);
    __shared__ float r2[2];
    if ((threadIdx.x & 63) == 0) r2[threadIdx.x >> 6] = v;
    __syncthreads();
    if (threadIdx.x == 0) out[0] = r2[0] + r2[1];
}

// Upper-triangular tiled syrk in fp4 (scale 1.0) with fused hinge reduction.
// 64x64 tiles -> 2080 blocks (8.1/CU grid); LDS 16 KB double-buffered and
// launch_bounds(256,6) -> ~6 resident blocks/CU = 24 waves/CU: TLP hides the
// load latency that capped rounds 3-5 (2 blocks/CU). 4 waves in 2x2, each one
// 32x32 quadrant via mfma_scale_f32_32x32x64_f8f6f4. Counted vmcnt(2) 2-phase
// pipeline; 16B-granule swizzle on both sides (rule #21).
__global__ __launch_bounds__(256, 6) void gram_hinge_kernel(const uchar* __restrict__ xq,
                                                            const float* __restrict__ sq,
                                                            float* __restrict__ part) {
    // XCD-aware chunking: 2080 = 8 * 260 exactly -> bijective.
    const int wgid = (blockIdx.x & 7) * (NBLK / 8) + (blockIdx.x >> 3);
    // Closed-form triangular decode: run for bi=b starts at b*NT - b(b-1)/2;
    // disc at run starts is the perfect square (129-2b)^2 -> exact f32 sqrt.
    int b = (int)((129.0f - sqrtf((float)(16641 - 8 * wgid))) * 0.5f);
    while (wgid < b * NT - b * (b - 1) / 2) --b;
    while (wgid >= (b + 1) * NT - (b + 1) * b / 2) ++b;
    const int bi = b;
    const int bj = b + (wgid - (b * NT - b * (b - 1) / 2));

    __shared__ uchar As[2][TS * 64];   // 2 x 4 KB (64 rows x 64 B = 128 fp4 K)
    __shared__ uchar Bs[2][TS * 64];
    __shared__ float red[4];

    const int tid = threadIdx.x;
    const int lane = tid & 63, wid = tid >> 6;
    const int wr = wid >> 1, wc = wid & 1;
    const int hi = lane >> 5;

    const int rowA0 = bi * TS;
    const int rowB0 = bj * TS;

    f32x16 acc;
    #pragma unroll
    for (int e = 0; e < 16; ++e) acc[e] = 0.f;
    i32x8 av, bv;
    #pragma unroll
    for (int e = 4; e < 8; ++e) { av[e] = 0; bv[e] = 0; }

    // Stage one K-tile (A,B each 64 rows x 64 B = 256 granules of 16B; one per
    // thread). LDS granule G=tid (row=G>>2, cl=G&3) holds global granule
    // cg = cl ^ ((row>>1)&3). 1 A + 1 B instr per thread per step.
    const int srow = tid >> 2;
    const int scg = (tid & 3) ^ ((srow >> 1) & 3);
    auto STAGE = [&](int buf, int kt) {
        gload16(xq + (size_t)(rowA0 + srow) * 512 + kt * 64 + scg * 16, &As[buf][wid * 1024]);
        gload16(xq + (size_t)(rowB0 + srow) * 512 + kt * 64 + scg * 16, &Bs[buf][wid * 1024]);
    };

    auto COMPUTE = [&](int buf) {
        #pragma unroll
        for (int kk = 0; kk < 2; ++kk) {
            const int ra = wr * 32 + (lane & 31);
            const int rb = wc * 32 + (lane & 31);
            const int gpa = (kk * 2 + hi) ^ ((ra >> 1) & 3);
            const int gpb = (kk * 2 + hi) ^ ((rb >> 1) & 3);
            const i32x4 ta = *reinterpret_cast<const i32x4*>(&As[buf][ra * 64 + gpa * 16]);
            const i32x4 tb = *reinterpret_cast<const i32x4*>(&Bs[buf][rb * 64 + gpb * 16]);
            av[0] = ta[0]; av[1] = ta[1]; av[2] = ta[2]; av[3] = ta[3];
            bv[0] = tb[0]; bv[1] = tb[1]; bv[2] = tb[2]; bv[3] = tb[3];
            acc = __builtin_amdgcn_mfma_scale_f32_32x32x64_f8f6f4(
                av, bv, acc, 4, 4,                 // cbsz=fp4, blgp=fp4
                0, 0x7f7f7f7f, 0, 0x7f7f7f7f);     // scale = 1.0
        }
    };

    STAGE(0, 0);
    for (int kt = 0; kt < NSTEP - 1; ++kt) {
        STAGE((kt + 1) & 1, kt + 1);                      // 2 new vmem ops in flight
        asm volatile("s_waitcnt vmcnt(2)" ::: "memory");  // cur tile's 2 oldest done
        __builtin_amdgcn_s_barrier();
        __builtin_amdgcn_sched_barrier(0);
        COMPUTE(kt & 1);
        __builtin_amdgcn_sched_barrier(0);
        __builtin_amdgcn_s_barrier();                     // reads done -> overwrite ok
    }
    asm volatile("s_waitcnt vmcnt(0)" ::: "memory");
    __builtin_amdgcn_s_barrier();
    __builtin_amdgcn_sched_barrier(0);
    COMPUTE((NSTEP - 1) & 1);

    // Fused epilogue: d2 = sq[i] + sq[j] - 2*g ; hinge; mask i<j ; reduce.
    // C/D layout (32x32): col = lane&31, row = (r&3) + 8*(r>>2) + 4*(lane>>5)  [m74/m101]
    float local = 0.f;
    const int jcol = rowB0 + wc * 32 + (lane & 31);
    const float sqj = sq[jcol];
    const int ibase = rowA0 + wr * 32 + 4 * hi;
    if (bi != bj) {
        #pragma unroll
        for (int r = 0; r < 16; ++r) {
            const int i = ibase + (r & 3) + 8 * (r >> 2);
            const float d2 = sq[i] + sqj - 2.f * acc[r];
            local += fmaxf(MARGIN - sqrtf(fmaxf(d2, 0.f)), 0.f);
        }
    } else {
        #pragma unroll
        for (int r = 0; r < 16; ++r) {
            const int i = ibase + (r & 3) + 8 * (r >> 2);
            if (i < jcol) {
                const float d2 = sq[i] + sqj - 2.f * acc[r];
                local += fmaxf(MARGIN - sqrtf(fmaxf(d2, 0.f)), 0.f);
            }
        }
    }
    #pragma unroll
    for (int off = 32; off > 0; off >>= 1) local += __shfl_down(local, off);
    if (lane == 0) red[wid] = local;
    __syncthreads();
    if (tid == 0) atomicAdd(&part[(wgid & (NPART - 1)) * 16],
                            red[0] + red[1] + red[2] + red[3]);
}

extern "C" void kernel_launch(void* const* d_in, const int* in_sizes, int n_in,
                              void* d_out, int out_size, void* d_ws, size_t ws_size,
                              hipStream_t stream) {
    const float* x = (const float*)d_in[0];
    float* out = (float*)d_out;
    uchar* xq = (uchar*)d_ws;                                        // 2 MB fp4 matrix
    float* sq = (float*)((char*)d_ws + (size_t)NC * 512);            // 16 KB row norms
    float* part = (float*)((char*)d_ws + (size_t)NC * 512 + 16384);  // 8 KB partials

    cast_sq_kernel<<<512, 256, 0, stream>>>(x, xq, sq, part);
    gram_hinge_kernel<<<NBLK, 256, 0, stream>>>(xq, sq, part);
    final_kernel<<<1, NPART, 0, stream>>>(part, out);
}

// Round 7
// 27.520 us; speedup vs baseline: 2.1093x; 1.0033x over previous
//
#include <hip/hip_runtime.h>
#include <hip/hip_bf16.h>

#define NC 4096
#define NK 1024
#define TS 64                      // tile size (rows and cols)
#define NT (NC / TS)               // 64 tiles per dim
#define NBLK (NT * (NT + 1) / 2)   // 2080 upper-triangular blocks = 8 XCDs * 260
#define NPART 128                  // scattered partial-sum slots (cacheline-spaced)

static constexpr float MARGIN = 0.0001f;

typedef __attribute__((ext_vector_type(4))) int i32x4;
typedef __attribute__((ext_vector_type(8))) int i32x8;
typedef __attribute__((ext_vector_type(16))) float f32x16;

// fp4 e2m1 quantize (round to nearest via thresholds): {0,.5,1,1.5,2,3,4,6}, sign bit 3.
__device__ inline uint q4(float x) {
    const float a = fabsf(x);
    uint c = (a >= 0.25f) + (a >= 0.75f) + (a >= 1.25f) + (a >= 1.75f) +
             (a >= 2.5f) + (a >= 3.5f) + (a >= 5.0f);
    return c | (x < 0.f ? 8u : 0u);
}

// Fragment-major fp4 layout: for row r (group g=r>>5, rr=r&31) and K-element k
// (byte b=k>>1, chunk q=b>>5, half h=(b>>4)&1, lo=b&15):
//   addr = (g*16 + q)*1024 + (h*32 + rr)*16 + lo
// A wave's MFMA fragment (group g, chunk q) is then the contiguous 1 KB at
// (g*16+q)*1024 + lane*16  -> one coalesced global_load_dwordx4, no LDS needed.
//
// 512 blocks x 4 waves; each wave quantizes 2 full rows and writes the exact
// f32 row norm. Block 0 also zeroes the partial slots.
__global__ __launch_bounds__(256) void cast_sq_kernel(const float* __restrict__ x,
                                                      uchar* __restrict__ xq2,
                                                      float* __restrict__ sq,
                                                      float* __restrict__ part) {
    const int tid = threadIdx.x, lane = tid & 63, wid = tid >> 6;
    if (blockIdx.x == 0 && tid < NPART) part[tid * 16] = 0.f;
    const int wg = blockIdx.x * 4 + wid;   // 2048 waves
    #pragma unroll
    for (int it = 0; it < 2; ++it) {
        const int row = wg + it * 2048;
        const int g = row >> 5, rr = row & 31;
        float s = 0.f;
        #pragma unroll
        for (int c = 0; c < 4; ++c) {
            const float4 v = reinterpret_cast<const float4*>(x + (size_t)row * NK)[lane + c * 64];
            s += v.x * v.x + v.y * v.y + v.z * v.z + v.w * v.w;
            const ushort u = (ushort)(q4(v.x) | (q4(v.y) << 4) | (q4(v.z) << 8) | (q4(v.w) << 12));
            // this ushort covers K-bytes b0..b0+1, b0 = 2*(lane + 64*c)
            const int q = 4 * c + (lane >> 4);
            const int h = (lane >> 3) & 1;
            const int lo = 2 * (lane & 7);
            *reinterpret_cast<ushort*>(xq2 + (size_t)(g * 16 + q) * 1024 + (h * 32 + rr) * 16 + lo) = u;
        }
        #pragma unroll
        for (int off = 32; off > 0; off >>= 1) s += __shfl_down(s, off);
        if (lane == 0) sq[row] = s;
    }
}

__global__ void final_kernel(const float* __restrict__ part, float* __restrict__ out) {
    float v = part[threadIdx.x * 16];
    #pragma unroll
    for (int off = 32; off > 0; off >>= 1) v += __shfl_down(v, off);
    __shared__ float r2[2];
    if ((threadIdx.x & 63) == 0) r2[threadIdx.x >> 6] = v;
    __syncthreads();
    if (threadIdx.x == 0) out[0] = r2[0] + r2[1];
}

// Upper-triangular tiled syrk in fp4 (scale 1.0) with fused hinge reduction.
// NO LDS, NO barriers: fragment-major layout makes every MFMA operand one
// coalesced global_load_dwordx4 from the L2-resident 2 MB matrix. Each of the
// 4 waves (2x2 quadrants of the 64x64 tile) is a straight line of 32
// independent loads + 16 chained MFMAs -> ILP + 16 waves/CU TLP hide latency.
__global__ __launch_bounds__(256, 4) void gram_hinge_kernel(const uchar* __restrict__ xq2,
                                                            const float* __restrict__ sq,
                                                            float* __restrict__ part) {
    // XCD-aware chunking: 2080 = 8 * 260 exactly -> bijective.
    const int wgid = (blockIdx.x & 7) * (NBLK / 8) + (blockIdx.x >> 3);
    // Closed-form triangular decode (runs of bj for each bi), +/-1 fixup.
    int b = (int)((129.0f - sqrtf((float)(16641 - 8 * wgid))) * 0.5f);
    while (wgid < b * NT - b * (b - 1) / 2) --b;
    while (wgid >= (b + 1) * NT - (b + 1) * b / 2) ++b;
    const int bi = b;
    const int bj = b + (wgid - (b * NT - b * (b - 1) / 2));

    const int tid = threadIdx.x;
    const int lane = tid & 63, wid = tid >> 6;
    const int wr = wid >> 1, wc = wid & 1;
    const int hi = lane >> 5;

    const int ga = bi * 2 + wr;   // 32-row group of this wave's A quadrant
    const int gb = bj * 2 + wc;
    const uchar* pa = xq2 + (size_t)ga * 16384 + lane * 16;
    const uchar* pb = xq2 + (size_t)gb * 16384 + lane * 16;

    f32x16 acc;
    #pragma unroll
    for (int e = 0; e < 16; ++e) acc[e] = 0.f;
    i32x8 av, bv;
    #pragma unroll
    for (int e = 4; e < 8; ++e) { av[e] = 0; bv[e] = 0; }

    #pragma unroll
    for (int q = 0; q < 16; ++q) {
        const i32x4 ta = *reinterpret_cast<const i32x4*>(pa + q * 1024);
        const i32x4 tb = *reinterpret_cast<const i32x4*>(pb + q * 1024);
        av[0] = ta[0]; av[1] = ta[1]; av[2] = ta[2]; av[3] = ta[3];
        bv[0] = tb[0]; bv[1] = tb[1]; bv[2] = tb[2]; bv[3] = tb[3];
        acc = __builtin_amdgcn_mfma_scale_f32_32x32x64_f8f6f4(
            av, bv, acc, 4, 4,                 // cbsz=fp4, blgp=fp4
            0, 0x7f7f7f7f, 0, 0x7f7f7f7f);     // scale = 1.0
    }

    // Fused epilogue: d2 = sq[i] + sq[j] - 2*g ; hinge; mask i<j ; reduce.
    // C/D layout (32x32): col = lane&31, row = (r&3) + 8*(r>>2) + 4*(lane>>5)  [m74/m101]
    float local = 0.f;
    const int jcol = bj * TS + wc * 32 + (lane & 31);
    const float sqj = sq[jcol];
    const int ibase = bi * TS + wr * 32 + 4 * hi;
    if (bi != bj) {
        #pragma unroll
        for (int r = 0; r < 16; ++r) {
            const int i = ibase + (r & 3) + 8 * (r >> 2);
            const float d2 = sq[i] + sqj - 2.f * acc[r];
            local += fmaxf(MARGIN - sqrtf(fmaxf(d2, 0.f)), 0.f);
        }
    } else {
        #pragma unroll
        for (int r = 0; r < 16; ++r) {
            const int i = ibase + (r & 3) + 8 * (r >> 2);
            if (i < jcol) {
                const float d2 = sq[i] + sqj - 2.f * acc[r];
                local += fmaxf(MARGIN - sqrtf(fmaxf(d2, 0.f)), 0.f);
            }
        }
    }
    #pragma unroll
    for (int off = 32; off > 0; off >>= 1) local += __shfl_down(local, off);
    __shared__ float red[4];
    if (lane == 0) red[wid] = local;
    __syncthreads();
    if (tid == 0) atomicAdd(&part[(wgid & (NPART - 1)) * 16],
                            red[0] + red[1] + red[2] + red[3]);
}

extern "C" void kernel_launch(void* const* d_in, const int* in_sizes, int n_in,
                              void* d_out, int out_size, void* d_ws, size_t ws_size,
                              hipStream_t stream) {
    const float* x = (const float*)d_in[0];
    float* out = (float*)d_out;
    uchar* xq2 = (uchar*)d_ws;                                       // 2 MB fp4, fragment-major
    float* sq = (float*)((char*)d_ws + (size_t)NC * 512);            // 16 KB row norms
    float* part = (float*)((char*)d_ws + (size_t)NC * 512 + 16384);  // 8 KB partials

    cast_sq_kernel<<<512, 256, 0, stream>>>(x, xq2, sq, part);
    gram_hinge_kernel<<<NBLK, 256, 0, stream>>>(xq2, sq, part);
    final_kernel<<<1, NPART, 0, stream>>>(part, out);
}